// Round 4
// baseline (9717.158 us; speedup 1.0000x reference)
//
#include <hip/hip_runtime.h>

// ---- problem constants ----
#define BB 64
#define TLEN 256
#define HH 512
#define GG 1536     // 3*H
#define EPAD 320    // E=300 padded to mult of 64
#define NN 3072     // 2*G (both directions stacked)
#define MM 16384    // T*B

typedef __attribute__((ext_vector_type(8))) __fp16 half8;
typedef __attribute__((ext_vector_type(4))) __fp16 half4;
typedef __attribute__((ext_vector_type(4))) float floatx4;

// ---- embedding gather + K-pad + fp32->fp16: e[t*64+b][0..320) ----
__global__ __launch_bounds__(256) void g2_embed(const int* __restrict__ x,
                                                const float* __restrict__ emb,
                                                __fp16* __restrict__ e) {
  int idx = blockIdx.x * 256 + threadIdx.x;   // chunk of 4 elems; total 16384*80
  int row = idx / 80;
  int c = idx - row * 80;
  int t = row >> 6, b = row & 63;
  half4 v = {0, 0, 0, 0};
  if (c < 75) {
    int xi = x[b * TLEN + t];
    float4 f = *(const float4*)&emb[(long)xi * 300 + c * 4];
    v[0] = (__fp16)f.x; v[1] = (__fp16)f.y; v[2] = (__fp16)f.z; v[3] = (__fp16)f.w;
  }
  *(half4*)&e[row * EPAD + c * 4] = v;
}

// ---- pad + convert w_ih0 [3072,300] fp32 -> [3072,320] fp16 ----
__global__ __launch_bounds__(256) void g2_padw(const float* __restrict__ w,
                                               __fp16* __restrict__ wp) {
  int idx = blockIdx.x * 256 + threadIdx.x;   // total 3072*80
  int row = idx / 80;
  int c = idx - row * 80;
  half4 v = {0, 0, 0, 0};
  if (c < 75) {
    float4 f = *(const float4*)&w[(long)row * 300 + c * 4];
    v[0] = (__fp16)f.x; v[1] = (__fp16)f.y; v[2] = (__fp16)f.z; v[3] = (__fp16)f.w;
  }
  *(half4*)&wp[row * EPAD + c * 4] = v;
}

// ---- fp32 -> fp16 bulk convert (chunks of 8) ----
__global__ __launch_bounds__(256) void g2_cvt(const float* __restrict__ src,
                                              __fp16* __restrict__ dst) {
  long idx = (long)blockIdx.x * 256 + threadIdx.x;
  float4 a = *(const float4*)&src[idx * 8];
  float4 b = *(const float4*)&src[idx * 8 + 4];
  half8 o;
  o[0] = (__fp16)a.x; o[1] = (__fp16)a.y; o[2] = (__fp16)a.z; o[3] = (__fp16)a.w;
  o[4] = (__fp16)b.x; o[5] = (__fp16)b.y; o[6] = (__fp16)b.z; o[7] = (__fp16)b.w;
  *(half8*)&dst[idx * 8] = o;
}

// ---- TN GEMM: C[M,N] fp16 = A[M,Kp] fp16 x W[N,Kp] fp16^T + bias[N](fp32) ----
// 128x128 tile, BK=64, 256 thr (4 waves, each 64x64), m97-pattern MFMA path.
__global__ __launch_bounds__(256) void g2_gemm(const __fp16* __restrict__ A,
                                               const __fp16* __restrict__ W,
                                               const float* __restrict__ bias,
                                               __fp16* __restrict__ C,
                                               int M, int N, int Kp) {
  __shared__ __fp16 As[128][72];
  __shared__ __fp16 Ws[128][72];
  const int nTiles = N >> 7;
  const int m0 = (blockIdx.x / nTiles) << 7;
  const int n0 = (blockIdx.x % nTiles) << 7;
  const int tid = threadIdx.x;
  const int lane = tid & 63, wv = tid >> 6;
  const int wm = (wv >> 1) << 6, wn = (wv & 1) << 6;
  const int nsub = lane & 15, quad = lane >> 4;

  floatx4 acc[4][4];
#pragma unroll
  for (int i = 0; i < 4; i++)
#pragma unroll
    for (int j = 0; j < 4; j++) acc[i][j] = (floatx4){0.f, 0.f, 0.f, 0.f};

  const int lr = tid >> 3;          // 0..31
  const int lc = (tid & 7) << 3;    // 0..56 step 8
  for (int ko = 0; ko < Kp; ko += 64) {
#pragma unroll
    for (int p = 0; p < 4; p++) {
      int r = lr + p * 32;
      *(half8*)&As[r][lc] = *(const half8*)&A[(long)(m0 + r) * Kp + ko + lc];
      *(half8*)&Ws[r][lc] = *(const half8*)&W[(long)(n0 + r) * Kp + ko + lc];
    }
    __syncthreads();
#pragma unroll
    for (int kk = 0; kk < 64; kk += 32) {
      half8 af[4], bf[4];
      const int kr = kk + (quad << 3);
#pragma unroll
      for (int i = 0; i < 4; i++) af[i] = *(const half8*)&As[wm + i * 16 + nsub][kr];
#pragma unroll
      for (int j = 0; j < 4; j++) bf[j] = *(const half8*)&Ws[wn + j * 16 + nsub][kr];
#pragma unroll
      for (int i = 0; i < 4; i++)
#pragma unroll
        for (int j = 0; j < 4; j++)
          acc[i][j] = __builtin_amdgcn_mfma_f32_16x16x32_f16(af[i], bf[j], acc[i][j], 0, 0, 0);
    }
    __syncthreads();
  }
#pragma unroll
  for (int j = 0; j < 4; j++) {
    int col = n0 + wn + j * 16 + nsub;
    float bv = bias[col];
#pragma unroll
    for (int i = 0; i < 4; i++) {
      int rb = m0 + wm + i * 16 + (quad << 2);
#pragma unroll
      for (int ii = 0; ii < 4; ii++)
        C[(long)(rb + ii) * N + col] = (__fp16)(acc[i][j][ii] + bv);
    }
  }
}

// ---- persistent bidirectional GRU recurrence ----
// grid 128 WGs x 128 thr. WG = (dir d, batch-group g of 32 rows, unit-tile u of 16 units).
// Group (d,g) = 32 WGs sync per step via agent-scope counter; cross-WG h traffic
// is volatile (bypass stale L1/L2) on top of fences.
__global__ __launch_bounds__(128) void g2_rnn(const float* __restrict__ whh,  // [2][1536][512] fp32
                                              const float* __restrict__ bhh,  // [2][1536] fp32
                                              const __fp16* __restrict__ xp,  // [256][64][3072]
                                              __fp16* __restrict__ hout,      // [256][64][1024]
                                              int* __restrict__ cnt) {        // [4][256]
  __shared__ __fp16 Wl[48][520];    // r(16),z(16),n(16) rows x 512 (+8 pad)
  __shared__ float hown[32][17];    // own h slice fp32 (exact self-recurrence path)
  const int bid = blockIdx.x;
  const int gi = bid & 3;           // d*2+g
  const int u = bid >> 2;           // 0..31
  const int d = gi >> 1, g = gi & 1;
  const int tid = threadIdx.x;
  const int lane = tid & 63, wv = tid >> 6;
  const int U0 = u << 4;
  const int nsub = lane & 15, quad = lane >> 4;
  const int bq = (g << 5) + (wv << 4);   // this wave's global batch base

  const float* wd = whh + (long)d * (GG * HH);
  for (int ch = tid; ch < 48 * 64; ch += 128) {
    int r = ch >> 6;
    int co = (ch & 63) << 3;
    int gr = (r < 16) ? (U0 + r) : ((r < 32) ? (HH + U0 + (r - 16)) : (2 * HH + U0 + (r - 32)));
    float4 a = *(const float4*)&wd[(long)gr * HH + co];
    float4 b = *(const float4*)&wd[(long)gr * HH + co + 4];
    half8 o;
    o[0] = (__fp16)a.x; o[1] = (__fp16)a.y; o[2] = (__fp16)a.z; o[3] = (__fp16)a.w;
    o[4] = (__fp16)b.x; o[5] = (__fp16)b.y; o[6] = (__fp16)b.z; o[7] = (__fp16)b.w;
    *(half8*)&Wl[r][co] = o;
  }
  for (int i = tid; i < 32 * 17; i += 128) ((float*)hown)[i] = 0.f;
  __syncthreads();

  const float bhr = bhh[d * GG + U0 + nsub];
  const float bhz = bhh[d * GG + HH + U0 + nsub];
  const float bhn = bhh[d * GG + 2 * HH + U0 + nsub];

  int* mycnt = cnt + gi * TLEN;

  for (int s = 0; s < TLEN; s++) {
    const int tt = d ? (TLEN - 1 - s) : s;
    // prefetch xp for this step (independent of h -> overlaps the poll below)
    float xr[4], xz[4], xn[4];
    {
      const __fp16* xb0 = xp + (long)(tt * BB) * NN + d * GG + U0 + nsub;
#pragma unroll
      for (int i = 0; i < 4; i++) {
        const __fp16* xb = xb0 + (long)(bq + (quad << 2) + i) * NN;
        xr[i] = (float)xb[0];
        xz[i] = (float)xb[HH];
        xn[i] = (float)xb[2 * HH];
      }
    }
    floatx4 ar = {0.f, 0.f, 0.f, 0.f}, az = ar, an = ar;
    if (s > 0) {
      if (tid == 0) {
        while (__hip_atomic_load(&mycnt[s - 1], __ATOMIC_ACQUIRE, __HIP_MEMORY_SCOPE_AGENT) < 32)
          __builtin_amdgcn_s_sleep(1);
      }
      __syncthreads();
      __threadfence();   // acquire side: make group's h(t-1) visible
      const int pt = d ? (tt + 1) : (tt - 1);
      const __fp16* hb = hout + ((long)(pt * BB + bq + nsub) * 1024) + d * HH + (quad << 3);
#pragma unroll
      for (int kk = 0; kk < HH; kk += 32) {
        half8 af = *(volatile const half8*)&hb[kk];   // force coherent read
        half8 br = *(const half8*)&Wl[nsub][kk + (quad << 3)];
        half8 bz = *(const half8*)&Wl[16 + nsub][kk + (quad << 3)];
        half8 bn = *(const half8*)&Wl[32 + nsub][kk + (quad << 3)];
        ar = __builtin_amdgcn_mfma_f32_16x16x32_f16(af, br, ar, 0, 0, 0);
        az = __builtin_amdgcn_mfma_f32_16x16x32_f16(af, bz, az, 0, 0, 0);
        an = __builtin_amdgcn_mfma_f32_16x16x32_f16(af, bn, an, 0, 0, 0);
      }
    }
    __fp16* ho = hout + (long)(tt * BB) * 1024 + d * HH + U0 + nsub;
#pragma unroll
    for (int i = 0; i < 4; i++) {
      int brow = (wv << 4) + (quad << 2) + i;   // 0..31 within group
      float grv = ar[i] + xr[i] + bhr;
      float gzv = az[i] + xz[i] + bhz;
      float gnv = an[i] + bhn;                  // recurrent part of n-gate (+b_hh)
      float rg = 1.f / (1.f + __expf(-grv));
      float zg = 1.f / (1.f + __expf(-gzv));
      float ex = __expf(2.f * (xn[i] + rg * gnv));
      float ng = 1.f - 2.f / (ex + 1.f);        // tanh
      float hold = hown[brow][nsub];
      float hnew = (1.f - zg) * ng + zg * hold;
      hown[brow][nsub] = hnew;
      *(volatile __fp16*)&ho[(long)((g << 5) + brow) * 1024] = (__fp16)hnew;  // write-through
    }
    __threadfence();       // release own slice
    __syncthreads();
    if (tid == 0)
      __hip_atomic_fetch_add(&mycnt[s], 1, __ATOMIC_RELEASE, __HIP_MEMORY_SCOPE_AGENT);
  }
}

// ---- max-pool over T ----
__global__ __launch_bounds__(256) void g2_pool(const __fp16* __restrict__ h1,
                                               float* __restrict__ pooled) {
  int b = blockIdx.x;
  int j0 = threadIdx.x * 4;
  float m[4] = {-3e38f, -3e38f, -3e38f, -3e38f};
  const __fp16* p = h1 + b * 1024 + j0;
  for (int t = 0; t < TLEN; t++) {
    half4 v = *(const half4*)(p + (long)t * BB * 1024);
#pragma unroll
    for (int q = 0; q < 4; q++) m[q] = fmaxf(m[q], (float)v[q]);
  }
  float* o = pooled + b * 1024 + j0;
#pragma unroll
  for (int q = 0; q < 4; q++) o[q] = m[q];
}

// ---- classifier head (all fp32) ----
__global__ __launch_bounds__(128) void g2_head(const float* __restrict__ pooled,
                                               const float* __restrict__ w1,
                                               const float* __restrict__ b1,
                                               const float* __restrict__ w2,
                                               const float* __restrict__ b2,
                                               float* __restrict__ out) {
  __shared__ float pl[1024];
  __shared__ float hid[128];
  int b = blockIdx.x, j = threadIdx.x;
  for (int k = j; k < 1024; k += 128) pl[k] = pooled[b * 1024 + k];
  __syncthreads();
  float acc = b1[j];
  const float* wr = w1 + (long)j * 1024;
  for (int k = 0; k < 1024; k += 4) {
    float4 w = *(const float4*)&wr[k];
    acc += pl[k] * w.x + pl[k + 1] * w.y + pl[k + 2] * w.z + pl[k + 3] * w.w;
  }
  hid[j] = fmaxf(acc, 0.f);
  __syncthreads();
  if (j < 2) {
    float a = b2[j];
    for (int k = 0; k < 128; k++) a += hid[k] * w2[j * 128 + k];
    out[b * 2 + j] = a;
  }
}

extern "C" void kernel_launch(void* const* d_in, const int* in_sizes, int n_in,
                              void* d_out, int out_size, void* d_ws, size_t ws_size,
                              hipStream_t stream) {
  (void)in_sizes; (void)n_in; (void)out_size; (void)ws_size;
  const int* x = (const int*)d_in[0];
  const float* emb = (const float*)d_in[1];
  const float* w_ih0 = (const float*)d_in[2];
  const float* w_hh0 = (const float*)d_in[3];
  const float* b_ih0 = (const float*)d_in[4];
  const float* b_hh0 = (const float*)d_in[5];
  const float* w_ih1 = (const float*)d_in[6];
  const float* w_hh1 = (const float*)d_in[7];
  const float* b_ih1 = (const float*)d_in[8];
  const float* b_hh1 = (const float*)d_in[9];
  const float* w1 = (const float*)d_in[10];
  const float* b1 = (const float*)d_in[11];
  const float* w2 = (const float*)d_in[12];
  const float* b2 = (const float*)d_in[13];

  // ---- workspace layout (total 186,785,792 B ~= 178 MiB) ----
  char* ws = (char*)d_ws;
  __fp16* xp = (__fp16*)(ws + 0);                  // 16384*3072*2 = 100,663,296
  __fp16* h0 = (__fp16*)(ws + 100663296);          // 16384*1024*2 =  33,554,432
  __fp16* h1 = (__fp16*)(ws + 134217728);          //                 33,554,432
  __fp16* e_pad = (__fp16*)(ws + 167772160);       // 16384*320*2  =  10,485,760
  __fp16* w0p = (__fp16*)(ws + 178257920);         // 3072*320*2   =   1,966,080
  __fp16* w1c = (__fp16*)(ws + 180224000);         // 3072*1024*2  =   6,291,456
  float* pooled = (float*)(ws + 186515456);        // 64*1024*4    =     262,144
  int* flags = (int*)(ws + 186777600);             //                      8,192

  hipMemsetAsync(flags, 0, 8192, stream);
  g2_embed<<<5120, 256, 0, stream>>>(x, emb, e_pad);
  g2_padw<<<960, 256, 0, stream>>>(w_ih0, w0p);
  g2_cvt<<<1536, 256, 0, stream>>>(w_ih1, w1c);    // 3,145,728 / 8 / 256
  g2_gemm<<<3072, 256, 0, stream>>>(e_pad, w0p, b_ih0, xp, MM, NN, EPAD);
  g2_rnn<<<128, 128, 0, stream>>>(w_hh0, b_hh0, xp, h0, flags);
  g2_gemm<<<3072, 256, 0, stream>>>(h0, w1c, b_ih1, xp, MM, NN, 1024);
  g2_rnn<<<128, 128, 0, stream>>>(w_hh1, b_hh1, xp, h1, flags + 1024);
  g2_pool<<<64, 256, 0, stream>>>(h1, pooled);
  g2_head<<<64, 128, 0, stream>>>(pooled, w1, b1, w2, b2, (float*)d_out);
}

// Round 6
// 4459.137 us; speedup vs baseline: 2.1792x; 2.1792x over previous
//
#include <hip/hip_runtime.h>

// ---- problem constants ----
#define BB 64
#define TLEN 256
#define HH 512
#define GG 1536     // 3*H
#define EPAD 320    // E=300 padded to mult of 64
#define NN 3072     // 2*G (both directions stacked)
#define MM 16384    // T*B

typedef __attribute__((ext_vector_type(8))) __fp16 half8;
typedef __attribute__((ext_vector_type(4))) __fp16 half4;
typedef __attribute__((ext_vector_type(4))) float floatx4;

// ---- embedding gather + K-pad + fp32->fp16: e[t*64+b][0..320) ----
__global__ __launch_bounds__(256) void g2_embed(const int* __restrict__ x,
                                                const float* __restrict__ emb,
                                                __fp16* __restrict__ e) {
  int idx = blockIdx.x * 256 + threadIdx.x;   // chunk of 4 elems; total 16384*80
  int row = idx / 80;
  int c = idx - row * 80;
  int t = row >> 6, b = row & 63;
  half4 v = {0, 0, 0, 0};
  if (c < 75) {
    int xi = x[b * TLEN + t];
    float4 f = *(const float4*)&emb[(long)xi * 300 + c * 4];
    v[0] = (__fp16)f.x; v[1] = (__fp16)f.y; v[2] = (__fp16)f.z; v[3] = (__fp16)f.w;
  }
  *(half4*)&e[row * EPAD + c * 4] = v;
}

// ---- pad + convert w_ih0 [3072,300] fp32 -> [3072,320] fp16 ----
__global__ __launch_bounds__(256) void g2_padw(const float* __restrict__ w,
                                               __fp16* __restrict__ wp) {
  int idx = blockIdx.x * 256 + threadIdx.x;   // total 3072*80
  int row = idx / 80;
  int c = idx - row * 80;
  half4 v = {0, 0, 0, 0};
  if (c < 75) {
    float4 f = *(const float4*)&w[(long)row * 300 + c * 4];
    v[0] = (__fp16)f.x; v[1] = (__fp16)f.y; v[2] = (__fp16)f.z; v[3] = (__fp16)f.w;
  }
  *(half4*)&wp[row * EPAD + c * 4] = v;
}

// ---- fp32 -> fp16 bulk convert (chunks of 8) ----
__global__ __launch_bounds__(256) void g2_cvt(const float* __restrict__ src,
                                              __fp16* __restrict__ dst) {
  long idx = (long)blockIdx.x * 256 + threadIdx.x;
  float4 a = *(const float4*)&src[idx * 8];
  float4 b = *(const float4*)&src[idx * 8 + 4];
  half8 o;
  o[0] = (__fp16)a.x; o[1] = (__fp16)a.y; o[2] = (__fp16)a.z; o[3] = (__fp16)a.w;
  o[4] = (__fp16)b.x; o[5] = (__fp16)b.y; o[6] = (__fp16)b.z; o[7] = (__fp16)b.w;
  *(half8*)&dst[idx * 8] = o;
}

// ---- TN GEMM: C[M,N] fp16 = A[M,Kp] fp16 x W[N,Kp] fp16^T + bias[N](fp32) ----
__global__ __launch_bounds__(256) void g2_gemm(const __fp16* __restrict__ A,
                                               const __fp16* __restrict__ W,
                                               const float* __restrict__ bias,
                                               __fp16* __restrict__ C,
                                               int M, int N, int Kp) {
  __shared__ __fp16 As[128][72];
  __shared__ __fp16 Ws[128][72];
  const int nTiles = N >> 7;
  const int m0 = (blockIdx.x / nTiles) << 7;
  const int n0 = (blockIdx.x % nTiles) << 7;
  const int tid = threadIdx.x;
  const int lane = tid & 63, wv = tid >> 6;
  const int wm = (wv >> 1) << 6, wn = (wv & 1) << 6;
  const int nsub = lane & 15, quad = lane >> 4;

  floatx4 acc[4][4];
#pragma unroll
  for (int i = 0; i < 4; i++)
#pragma unroll
    for (int j = 0; j < 4; j++) acc[i][j] = (floatx4){0.f, 0.f, 0.f, 0.f};

  const int lr = tid >> 3;          // 0..31
  const int lc = (tid & 7) << 3;    // 0..56 step 8
  for (int ko = 0; ko < Kp; ko += 64) {
#pragma unroll
    for (int p = 0; p < 4; p++) {
      int r = lr + p * 32;
      *(half8*)&As[r][lc] = *(const half8*)&A[(long)(m0 + r) * Kp + ko + lc];
      *(half8*)&Ws[r][lc] = *(const half8*)&W[(long)(n0 + r) * Kp + ko + lc];
    }
    __syncthreads();
#pragma unroll
    for (int kk = 0; kk < 64; kk += 32) {
      half8 af[4], bf[4];
      const int kr = kk + (quad << 3);
#pragma unroll
      for (int i = 0; i < 4; i++) af[i] = *(const half8*)&As[wm + i * 16 + nsub][kr];
#pragma unroll
      for (int j = 0; j < 4; j++) bf[j] = *(const half8*)&Ws[wn + j * 16 + nsub][kr];
#pragma unroll
      for (int i = 0; i < 4; i++)
#pragma unroll
        for (int j = 0; j < 4; j++)
          acc[i][j] = __builtin_amdgcn_mfma_f32_16x16x32_f16(af[i], bf[j], acc[i][j], 0, 0, 0);
    }
    __syncthreads();
  }
#pragma unroll
  for (int j = 0; j < 4; j++) {
    int col = n0 + wn + j * 16 + nsub;
    float bv = bias[col];
#pragma unroll
    for (int i = 0; i < 4; i++) {
      int rb = m0 + wm + i * 16 + (quad << 2);
#pragma unroll
      for (int ii = 0; ii < 4; ii++)
        C[(long)(rb + ii) * N + col] = (__fp16)(acc[i][j][ii] + bv);
    }
  }
}

// ---- persistent bidirectional GRU recurrence ----
// grid 64 WGs x 256 thr. WG = (dir d, batch-group g of 32 rows, unit-tile uo of 32 units).
// Group (d,g) = 16 WGs sync per step via agent-scope counter (RELAXED poll + one
// acquire fence). Cross-WG h traffic: volatile (bypass non-coherent L1/L2).
__global__ __launch_bounds__(256) void g2_rnn(const float* __restrict__ whh,  // [2][1536][512] fp32
                                              const float* __restrict__ bhh,  // [2][1536] fp32
                                              const __fp16* __restrict__ xp,  // [256][64][3072]
                                              __fp16* __restrict__ hout,      // [256][64][1024]
                                              int* __restrict__ cnt) {        // [4][256]
  __shared__ __fp16 Wl[96][520];    // [gate*32 + ulocal][512 (+8 pad)]
  __shared__ float hown[32][33];    // own h slice fp32 [brow][ulocal]
  const int bid = blockIdx.x;
  const int gi = bid & 3;           // d*2+g
  const int uo = bid >> 2;          // 0..15
  const int d = gi >> 1, g = gi & 1;
  const int tid = threadIdx.x;
  const int lane = tid & 63, wv = tid >> 6;
  const int U0 = uo << 5;           // 32 units per WG
  const int mb = wv & 1, ut = wv >> 1;
  const int nsub = lane & 15, quad = lane >> 4;
  const int bq = (g << 5) + (mb << 4);   // wave's global batch base (16 rows)
  const int ul = (ut << 4) + nsub;       // wave's unit (local 0..31)

  // ---- one-time: load + convert weights [3 gates][32 units][512] into LDS ----
  const float* wd = whh + (long)d * (GG * HH);
  for (int idx = tid; idx < 96 * 64; idx += 256) {
    int r = idx >> 6;               // 0..95
    int c = (idx & 63) << 3;        // 0..504 step 8
    int gate = r >> 5, u2 = r & 31;
    const float* src = &wd[(long)(gate * HH + U0 + u2) * HH + c];
    float4 a = *(const float4*)&src[0];
    float4 b = *(const float4*)&src[4];
    half8 o;
    o[0] = (__fp16)a.x; o[1] = (__fp16)a.y; o[2] = (__fp16)a.z; o[3] = (__fp16)a.w;
    o[4] = (__fp16)b.x; o[5] = (__fp16)b.y; o[6] = (__fp16)b.z; o[7] = (__fp16)b.w;
    *(half8*)&Wl[r][c] = o;
  }
  for (int i = tid; i < 32 * 33; i += 256) ((float*)hown)[i] = 0.f;
  __syncthreads();

  const float bhr = bhh[d * GG + U0 + ul];
  const float bhz = bhh[d * GG + HH + U0 + ul];
  const float bhn = bhh[d * GG + 2 * HH + U0 + ul];

  int* mycnt = cnt + gi * TLEN;

  for (int s = 0; s < TLEN; s++) {
    const int tt = d ? (TLEN - 1 - s) : s;
    // prefetch xp for this step (independent of h -> overlaps the poll below)
    float xr[4], xz[4], xn[4];
    {
      const __fp16* xb0 = xp + (long)(tt * BB) * NN + d * GG + U0 + ul;
#pragma unroll
      for (int i = 0; i < 4; i++) {
        const __fp16* xb = xb0 + (long)(bq + (quad << 2) + i) * NN;
        xr[i] = (float)xb[0];
        xz[i] = (float)xb[HH];
        xn[i] = (float)xb[2 * HH];
      }
    }
    floatx4 ar = {0.f, 0.f, 0.f, 0.f}, az = ar, an = ar;
    if (s > 0) {
      if (tid == 0) {
        // RELAXED poll: no per-iteration cache invalidate; agent-scope atomic
        // load reads the coherence point directly.
        while (__hip_atomic_load(&mycnt[s - 1], __ATOMIC_RELAXED, __HIP_MEMORY_SCOPE_AGENT) < 16) {}
      }
      __syncthreads();
      __builtin_amdgcn_fence(__ATOMIC_ACQUIRE, "agent");  // one cache-inv per step
      const int pt = d ? (tt + 1) : (tt - 1);
      const __fp16* hb = hout + ((long)(pt * BB + bq + nsub) * 1024) + d * HH + (quad << 3);
      // preload ALL h fragments (16 b128 loads in flight -> one drain),
      // then run the MFMA loop from registers.
      half8 hreg[16];
#pragma unroll
      for (int kk = 0; kk < 16; kk++)
        hreg[kk] = *(volatile const half8*)&hb[kk * 32];
#pragma unroll
      for (int kk = 0; kk < 16; kk++) {
        const int kcol = (kk << 5) + (quad << 3);
        half8 br = *(const half8*)&Wl[(ut << 4) + nsub][kcol];
        half8 bz = *(const half8*)&Wl[32 + (ut << 4) + nsub][kcol];
        half8 bn = *(const half8*)&Wl[64 + (ut << 4) + nsub][kcol];
        ar = __builtin_amdgcn_mfma_f32_16x16x32_f16(hreg[kk], br, ar, 0, 0, 0);
        az = __builtin_amdgcn_mfma_f32_16x16x32_f16(hreg[kk], bz, az, 0, 0, 0);
        an = __builtin_amdgcn_mfma_f32_16x16x32_f16(hreg[kk], bn, an, 0, 0, 0);
      }
    }
    // epilogue -> hown (fp32, exact self-recurrence path)
#pragma unroll
    for (int i = 0; i < 4; i++) {
      int brow = (mb << 4) + (quad << 2) + i;   // 0..31 within group
      float grv = ar[i] + xr[i] + bhr;
      float gzv = az[i] + xz[i] + bhz;
      float gnv = an[i] + bhn;                  // recurrent part of n-gate (+b_hh)
      float rg = 1.f / (1.f + __expf(-grv));
      float zg = 1.f / (1.f + __expf(-gzv));
      float ex = __expf(2.f * (xn[i] + rg * gnv));
      float ng = 1.f - 2.f / (ex + 1.f);        // tanh
      float hold = hown[brow][ul];
      hown[brow][ul] = (1.f - zg) * ng + zg * hold;
    }
    __syncthreads();
    // coalesced publish: 32 rows x 32 units as half8 volatile stores
    if (tid < 128) {
      int br = tid >> 2;            // 0..31
      int c = (tid & 3) << 3;       // 0..24 step 8
      half8 o;
#pragma unroll
      for (int q = 0; q < 8; q++) o[q] = (__fp16)hown[br][c + q];
      *(volatile half8*)&hout[(long)(tt * BB + (g << 5) + br) * 1024 + d * HH + U0 + c] = o;
    }
    __syncthreads();   // compiler emits vmcnt(0) drain before barrier -> stores visible
    if (tid == 0)
      __hip_atomic_fetch_add(&mycnt[s], 1, __ATOMIC_RELEASE, __HIP_MEMORY_SCOPE_AGENT);
  }
}

// ---- max-pool over T ----
__global__ __launch_bounds__(256) void g2_pool(const __fp16* __restrict__ h1,
                                               float* __restrict__ pooled) {
  int b = blockIdx.x;
  int j0 = threadIdx.x * 4;
  float m[4] = {-3e38f, -3e38f, -3e38f, -3e38f};
  const __fp16* p = h1 + b * 1024 + j0;
  for (int t = 0; t < TLEN; t++) {
    half4 v = *(const half4*)(p + (long)t * BB * 1024);
#pragma unroll
    for (int q = 0; q < 4; q++) m[q] = fmaxf(m[q], (float)v[q]);
  }
  float* o = pooled + b * 1024 + j0;
#pragma unroll
  for (int q = 0; q < 4; q++) o[q] = m[q];
}

// ---- classifier head (all fp32) ----
__global__ __launch_bounds__(128) void g2_head(const float* __restrict__ pooled,
                                               const float* __restrict__ w1,
                                               const float* __restrict__ b1,
                                               const float* __restrict__ w2,
                                               const float* __restrict__ b2,
                                               float* __restrict__ out) {
  __shared__ float pl[1024];
  __shared__ float hid[128];
  int b = blockIdx.x, j = threadIdx.x;
  for (int k = j; k < 1024; k += 128) pl[k] = pooled[b * 1024 + k];
  __syncthreads();
  float acc = b1[j];
  const float* wr = w1 + (long)j * 1024;
  for (int k = 0; k < 1024; k += 4) {
    float4 w = *(const float4*)&wr[k];
    acc += pl[k] * w.x + pl[k + 1] * w.y + pl[k + 2] * w.z + pl[k + 3] * w.w;
  }
  hid[j] = fmaxf(acc, 0.f);
  __syncthreads();
  if (j < 2) {
    float a = b2[j];
    for (int k = 0; k < 128; k++) a += hid[k] * w2[j * 128 + k];
    out[b * 2 + j] = a;
  }
}

extern "C" void kernel_launch(void* const* d_in, const int* in_sizes, int n_in,
                              void* d_out, int out_size, void* d_ws, size_t ws_size,
                              hipStream_t stream) {
  (void)in_sizes; (void)n_in; (void)out_size; (void)ws_size;
  const int* x = (const int*)d_in[0];
  const float* emb = (const float*)d_in[1];
  const float* w_ih0 = (const float*)d_in[2];
  const float* w_hh0 = (const float*)d_in[3];
  const float* b_ih0 = (const float*)d_in[4];
  const float* b_hh0 = (const float*)d_in[5];
  const float* w_ih1 = (const float*)d_in[6];
  const float* w_hh1 = (const float*)d_in[7];
  const float* b_ih1 = (const float*)d_in[8];
  const float* b_hh1 = (const float*)d_in[9];
  const float* w1 = (const float*)d_in[10];
  const float* b1 = (const float*)d_in[11];
  const float* w2 = (const float*)d_in[12];
  const float* b2 = (const float*)d_in[13];

  // ---- workspace layout (total 186,785,792 B ~= 178 MiB) ----
  char* ws = (char*)d_ws;
  __fp16* xp = (__fp16*)(ws + 0);                  // 16384*3072*2 = 100,663,296
  __fp16* h0 = (__fp16*)(ws + 100663296);          // 16384*1024*2 =  33,554,432
  __fp16* h1 = (__fp16*)(ws + 134217728);          //                 33,554,432
  __fp16* e_pad = (__fp16*)(ws + 167772160);       // 16384*320*2  =  10,485,760
  __fp16* w0p = (__fp16*)(ws + 178257920);         // 3072*320*2   =   1,966,080
  __fp16* w1c = (__fp16*)(ws + 180224000);         // 3072*1024*2  =   6,291,456
  float* pooled = (float*)(ws + 186515456);        // 64*1024*4    =     262,144
  int* flags = (int*)(ws + 186777600);             //                      8,192

  (void)hipMemsetAsync(flags, 0, 8192, stream);
  g2_embed<<<5120, 256, 0, stream>>>(x, emb, e_pad);
  g2_padw<<<960, 256, 0, stream>>>(w_ih0, w0p);
  g2_cvt<<<1536, 256, 0, stream>>>(w_ih1, w1c);
  g2_gemm<<<3072, 256, 0, stream>>>(e_pad, w0p, b_ih0, xp, MM, NN, EPAD);
  g2_rnn<<<64, 256, 0, stream>>>(w_hh0, b_hh0, xp, h0, flags);
  g2_gemm<<<3072, 256, 0, stream>>>(h0, w1c, b_ih1, xp, MM, NN, 1024);
  g2_rnn<<<64, 256, 0, stream>>>(w_hh1, b_hh1, xp, h1, flags + 1024);
  g2_pool<<<64, 256, 0, stream>>>(h1, pooled);
  g2_head<<<64, 128, 0, stream>>>(pooled, w1, b1, w2, b2, (float*)d_out);
}

// Round 7
// 3846.782 us; speedup vs baseline: 2.5260x; 1.1592x over previous
//
#include <hip/hip_runtime.h>

// ---- problem constants ----
#define BB 64
#define TLEN 256
#define HH 512
#define GG 1536     // 3*H
#define EPAD 320    // E=300 padded to mult of 64
#define NN 3072     // 2*G (both directions stacked)
#define MM 16384    // T*B

typedef __attribute__((ext_vector_type(8))) __fp16 half8;
typedef __attribute__((ext_vector_type(4))) __fp16 half4;
typedef __attribute__((ext_vector_type(4))) float floatx4;

// ---- embedding gather + K-pad + fp32->fp16: e[t*64+b][0..320) ----
__global__ __launch_bounds__(256) void g2_embed(const int* __restrict__ x,
                                                const float* __restrict__ emb,
                                                __fp16* __restrict__ e) {
  int idx = blockIdx.x * 256 + threadIdx.x;   // chunk of 4 elems; total 16384*80
  int row = idx / 80;
  int c = idx - row * 80;
  int t = row >> 6, b = row & 63;
  half4 v = {0, 0, 0, 0};
  if (c < 75) {
    int xi = x[b * TLEN + t];
    float4 f = *(const float4*)&emb[(long)xi * 300 + c * 4];
    v[0] = (__fp16)f.x; v[1] = (__fp16)f.y; v[2] = (__fp16)f.z; v[3] = (__fp16)f.w;
  }
  *(half4*)&e[row * EPAD + c * 4] = v;
}

// ---- pad + convert w_ih0 [3072,300] fp32 -> [3072,320] fp16 ----
__global__ __launch_bounds__(256) void g2_padw(const float* __restrict__ w,
                                               __fp16* __restrict__ wp) {
  int idx = blockIdx.x * 256 + threadIdx.x;   // total 3072*80
  int row = idx / 80;
  int c = idx - row * 80;
  half4 v = {0, 0, 0, 0};
  if (c < 75) {
    float4 f = *(const float4*)&w[(long)row * 300 + c * 4];
    v[0] = (__fp16)f.x; v[1] = (__fp16)f.y; v[2] = (__fp16)f.z; v[3] = (__fp16)f.w;
  }
  *(half4*)&wp[row * EPAD + c * 4] = v;
}

// ---- fp32 -> fp16 bulk convert (chunks of 8) ----
__global__ __launch_bounds__(256) void g2_cvt(const float* __restrict__ src,
                                              __fp16* __restrict__ dst) {
  long idx = (long)blockIdx.x * 256 + threadIdx.x;
  float4 a = *(const float4*)&src[idx * 8];
  float4 b = *(const float4*)&src[idx * 8 + 4];
  half8 o;
  o[0] = (__fp16)a.x; o[1] = (__fp16)a.y; o[2] = (__fp16)a.z; o[3] = (__fp16)a.w;
  o[4] = (__fp16)b.x; o[5] = (__fp16)b.y; o[6] = (__fp16)b.z; o[7] = (__fp16)b.w;
  *(half8*)&dst[idx * 8] = o;
}

// ---- TN GEMM: C[M,N] fp16 = A[M,Kp] fp16 x W[N,Kp] fp16^T + bias[N](fp32) ----
__global__ __launch_bounds__(256) void g2_gemm(const __fp16* __restrict__ A,
                                               const __fp16* __restrict__ W,
                                               const float* __restrict__ bias,
                                               __fp16* __restrict__ C,
                                               int M, int N, int Kp) {
  __shared__ __fp16 As[128][72];
  __shared__ __fp16 Ws[128][72];
  const int nTiles = N >> 7;
  const int m0 = (blockIdx.x / nTiles) << 7;
  const int n0 = (blockIdx.x % nTiles) << 7;
  const int tid = threadIdx.x;
  const int lane = tid & 63, wv = tid >> 6;
  const int wm = (wv >> 1) << 6, wn = (wv & 1) << 6;
  const int nsub = lane & 15, quad = lane >> 4;

  floatx4 acc[4][4];
#pragma unroll
  for (int i = 0; i < 4; i++)
#pragma unroll
    for (int j = 0; j < 4; j++) acc[i][j] = (floatx4){0.f, 0.f, 0.f, 0.f};

  const int lr = tid >> 3;          // 0..31
  const int lc = (tid & 7) << 3;    // 0..56 step 8
  for (int ko = 0; ko < Kp; ko += 64) {
#pragma unroll
    for (int p = 0; p < 4; p++) {
      int r = lr + p * 32;
      *(half8*)&As[r][lc] = *(const half8*)&A[(long)(m0 + r) * Kp + ko + lc];
      *(half8*)&Ws[r][lc] = *(const half8*)&W[(long)(n0 + r) * Kp + ko + lc];
    }
    __syncthreads();
#pragma unroll
    for (int kk = 0; kk < 64; kk += 32) {
      half8 af[4], bf[4];
      const int kr = kk + (quad << 3);
#pragma unroll
      for (int i = 0; i < 4; i++) af[i] = *(const half8*)&As[wm + i * 16 + nsub][kr];
#pragma unroll
      for (int j = 0; j < 4; j++) bf[j] = *(const half8*)&Ws[wn + j * 16 + nsub][kr];
#pragma unroll
      for (int i = 0; i < 4; i++)
#pragma unroll
        for (int j = 0; j < 4; j++)
          acc[i][j] = __builtin_amdgcn_mfma_f32_16x16x32_f16(af[i], bf[j], acc[i][j], 0, 0, 0);
    }
    __syncthreads();
  }
#pragma unroll
  for (int j = 0; j < 4; j++) {
    int col = n0 + wn + j * 16 + nsub;
    float bv = bias[col];
#pragma unroll
    for (int i = 0; i < 4; i++) {
      int rb = m0 + wm + i * 16 + (quad << 2);
#pragma unroll
      for (int ii = 0; ii < 4; ii++)
        C[(long)(rb + ii) * N + col] = (__fp16)(acc[i][j][ii] + bv);
    }
  }
}

// ---- persistent bidirectional GRU recurrence ----
// grid 64 WGs x 256 thr. WG = (dir d, batch-group g of 32 rows, unit-tile uo of 32 units).
// Group (d,g) = 16 WGs sync per step via agent-scope counter (RELAXED poll + one
// acquire fence). Producer h stores are volatile (write-through); consumer h
// loads are PLAIN (freshness guaranteed by the acquire fence's L1/L2 inv) so
// all 16 b128 loads pipeline instead of serializing on vmcnt drains.
__global__ __launch_bounds__(256) void g2_rnn(const float* __restrict__ whh,  // [2][1536][512] fp32
                                              const float* __restrict__ bhh,  // [2][1536] fp32
                                              const __fp16* __restrict__ xp,  // [256][64][3072]
                                              __fp16* __restrict__ hout,      // [256][64][1024]
                                              int* __restrict__ cnt) {        // [4][256]
  __shared__ __fp16 Wl[96][520];    // [gate*32 + ulocal][512 (+8 pad)]
  __shared__ float hown[32][33];    // own h slice fp32 [brow][ulocal]
  const int bid = blockIdx.x;
  const int gi = bid & 3;           // d*2+g
  const int uo = bid >> 2;          // 0..15
  const int d = gi >> 1, g = gi & 1;
  const int tid = threadIdx.x;
  const int lane = tid & 63, wv = tid >> 6;
  const int U0 = uo << 5;           // 32 units per WG
  const int mb = wv & 1, ut = wv >> 1;
  const int nsub = lane & 15, quad = lane >> 4;
  const int bq = (g << 5) + (mb << 4);   // wave's global batch base (16 rows)
  const int ul = (ut << 4) + nsub;       // wave's unit (local 0..31)

  // ---- one-time: load + convert weights [3 gates][32 units][512] into LDS ----
  const float* wd = whh + (long)d * (GG * HH);
  for (int idx = tid; idx < 96 * 64; idx += 256) {
    int r = idx >> 6;               // 0..95
    int c = (idx & 63) << 3;        // 0..504 step 8
    int gate = r >> 5, u2 = r & 31;
    const float* src = &wd[(long)(gate * HH + U0 + u2) * HH + c];
    float4 a = *(const float4*)&src[0];
    float4 b = *(const float4*)&src[4];
    half8 o;
    o[0] = (__fp16)a.x; o[1] = (__fp16)a.y; o[2] = (__fp16)a.z; o[3] = (__fp16)a.w;
    o[4] = (__fp16)b.x; o[5] = (__fp16)b.y; o[6] = (__fp16)b.z; o[7] = (__fp16)b.w;
    *(half8*)&Wl[r][c] = o;
  }
  for (int i = tid; i < 32 * 33; i += 256) ((float*)hown)[i] = 0.f;
  __syncthreads();

  const float bhr = bhh[d * GG + U0 + ul];
  const float bhz = bhh[d * GG + HH + U0 + ul];
  const float bhn = bhh[d * GG + 2 * HH + U0 + ul];

  int* mycnt = cnt + gi * TLEN;

  for (int s = 0; s < TLEN; s++) {
    const int tt = d ? (TLEN - 1 - s) : s;
    // prefetch xp for this step (independent of h -> overlaps the poll below)
    float xr[4], xz[4], xn[4];
    {
      const __fp16* xb0 = xp + (long)(tt * BB) * NN + d * GG + U0 + ul;
#pragma unroll
      for (int i = 0; i < 4; i++) {
        const __fp16* xb = xb0 + (long)(bq + (quad << 2) + i) * NN;
        xr[i] = (float)xb[0];
        xz[i] = (float)xb[HH];
        xn[i] = (float)xb[2 * HH];
      }
    }
    floatx4 ar = {0.f, 0.f, 0.f, 0.f}, az = ar, an = ar;
    if (s > 0) {
      if (tid == 0) {
        // RELAXED poll: no per-iteration cache invalidate.
        while (__hip_atomic_load(&mycnt[s - 1], __ATOMIC_RELAXED, __HIP_MEMORY_SCOPE_AGENT) < 16) {}
      }
      __syncthreads();
      __builtin_amdgcn_fence(__ATOMIC_ACQUIRE, "agent");  // one L1/L2 inv per step
      const int pt = d ? (tt + 1) : (tt - 1);
      const __fp16* hb = hout + ((long)(pt * BB + bq + nsub) * 1024) + d * HH + (quad << 3);
      // preload ALL h fragments — PLAIN loads (post-fence => fresh), fully
      // pipelined: ~1 LLC round trip total instead of 16 serialized ones.
      half8 hreg[16];
#pragma unroll
      for (int kk = 0; kk < 16; kk++)
        hreg[kk] = *(const half8*)&hb[kk * 32];
#pragma unroll
      for (int kk = 0; kk < 16; kk++) {
        const int kcol = (kk << 5) + (quad << 3);
        half8 br = *(const half8*)&Wl[(ut << 4) + nsub][kcol];
        half8 bz = *(const half8*)&Wl[32 + (ut << 4) + nsub][kcol];
        half8 bn = *(const half8*)&Wl[64 + (ut << 4) + nsub][kcol];
        ar = __builtin_amdgcn_mfma_f32_16x16x32_f16(hreg[kk], br, ar, 0, 0, 0);
        az = __builtin_amdgcn_mfma_f32_16x16x32_f16(hreg[kk], bz, az, 0, 0, 0);
        an = __builtin_amdgcn_mfma_f32_16x16x32_f16(hreg[kk], bn, an, 0, 0, 0);
      }
    }
    // epilogue -> hown (fp32, exact self-recurrence path)
#pragma unroll
    for (int i = 0; i < 4; i++) {
      int brow = (mb << 4) + (quad << 2) + i;   // 0..31 within group
      float grv = ar[i] + xr[i] + bhr;
      float gzv = az[i] + xz[i] + bhz;
      float gnv = an[i] + bhn;                  // recurrent part of n-gate (+b_hh)
      float rg = 1.f / (1.f + __expf(-grv));
      float zg = 1.f / (1.f + __expf(-gzv));
      float ex = __expf(2.f * (xn[i] + rg * gnv));
      float ng = 1.f - 2.f / (ex + 1.f);        // tanh
      float hold = hown[brow][ul];
      hown[brow][ul] = (1.f - zg) * ng + zg * hold;
    }
    __syncthreads();
    // coalesced publish: 32 rows x 32 units as half8 volatile (write-through) stores
    if (tid < 128) {
      int br = tid >> 2;            // 0..31
      int c = (tid & 3) << 3;       // 0..24 step 8
      half8 o;
#pragma unroll
      for (int q = 0; q < 8; q++) o[q] = (__fp16)hown[br][c + q];
      *(volatile half8*)&hout[(long)(tt * BB + (g << 5) + br) * 1024 + d * HH + U0 + c] = o;
    }
    __syncthreads();   // vmcnt(0) drain before barrier -> stores at LLC
    if (tid == 0)
      __hip_atomic_fetch_add(&mycnt[s], 1, __ATOMIC_RELEASE, __HIP_MEMORY_SCOPE_AGENT);
  }
}

// ---- max-pool over T ----
__global__ __launch_bounds__(256) void g2_pool(const __fp16* __restrict__ h1,
                                               float* __restrict__ pooled) {
  int b = blockIdx.x;
  int j0 = threadIdx.x * 4;
  float m[4] = {-3e38f, -3e38f, -3e38f, -3e38f};
  const __fp16* p = h1 + b * 1024 + j0;
  for (int t = 0; t < TLEN; t++) {
    half4 v = *(const half4*)(p + (long)t * BB * 1024);
#pragma unroll
    for (int q = 0; q < 4; q++) m[q] = fmaxf(m[q], (float)v[q]);
  }
  float* o = pooled + b * 1024 + j0;
#pragma unroll
  for (int q = 0; q < 4; q++) o[q] = m[q];
}

// ---- classifier head (all fp32) ----
__global__ __launch_bounds__(128) void g2_head(const float* __restrict__ pooled,
                                               const float* __restrict__ w1,
                                               const float* __restrict__ b1,
                                               const float* __restrict__ w2,
                                               const float* __restrict__ b2,
                                               float* __restrict__ out) {
  __shared__ float pl[1024];
  __shared__ float hid[128];
  int b = blockIdx.x, j = threadIdx.x;
  for (int k = j; k < 1024; k += 128) pl[k] = pooled[b * 1024 + k];
  __syncthreads();
  float acc = b1[j];
  const float* wr = w1 + (long)j * 1024;
  for (int k = 0; k < 1024; k += 4) {
    float4 w = *(const float4*)&wr[k];
    acc += pl[k] * w.x + pl[k + 1] * w.y + pl[k + 2] * w.z + pl[k + 3] * w.w;
  }
  hid[j] = fmaxf(acc, 0.f);
  __syncthreads();
  if (j < 2) {
    float a = b2[j];
    for (int k = 0; k < 128; k++) a += hid[k] * w2[j * 128 + k];
    out[b * 2 + j] = a;
  }
}

extern "C" void kernel_launch(void* const* d_in, const int* in_sizes, int n_in,
                              void* d_out, int out_size, void* d_ws, size_t ws_size,
                              hipStream_t stream) {
  (void)in_sizes; (void)n_in; (void)out_size; (void)ws_size;
  const int* x = (const int*)d_in[0];
  const float* emb = (const float*)d_in[1];
  const float* w_ih0 = (const float*)d_in[2];
  const float* w_hh0 = (const float*)d_in[3];
  const float* b_ih0 = (const float*)d_in[4];
  const float* b_hh0 = (const float*)d_in[5];
  const float* w_ih1 = (const float*)d_in[6];
  const float* w_hh1 = (const float*)d_in[7];
  const float* b_ih1 = (const float*)d_in[8];
  const float* b_hh1 = (const float*)d_in[9];
  const float* w1 = (const float*)d_in[10];
  const float* b1 = (const float*)d_in[11];
  const float* w2 = (const float*)d_in[12];
  const float* b2 = (const float*)d_in[13];

  // ---- workspace layout (total 186,785,792 B ~= 178 MiB) ----
  char* ws = (char*)d_ws;
  __fp16* xp = (__fp16*)(ws + 0);                  // 16384*3072*2 = 100,663,296
  __fp16* h0 = (__fp16*)(ws + 100663296);          // 16384*1024*2 =  33,554,432
  __fp16* h1 = (__fp16*)(ws + 134217728);          //                 33,554,432
  __fp16* e_pad = (__fp16*)(ws + 167772160);       // 16384*320*2  =  10,485,760
  __fp16* w0p = (__fp16*)(ws + 178257920);         // 3072*320*2   =   1,966,080
  __fp16* w1c = (__fp16*)(ws + 180224000);         // 3072*1024*2  =   6,291,456
  float* pooled = (float*)(ws + 186515456);        // 64*1024*4    =     262,144
  int* flags = (int*)(ws + 186777600);             //                      8,192

  (void)hipMemsetAsync(flags, 0, 8192, stream);
  g2_embed<<<5120, 256, 0, stream>>>(x, emb, e_pad);
  g2_padw<<<960, 256, 0, stream>>>(w_ih0, w0p);
  g2_cvt<<<1536, 256, 0, stream>>>(w_ih1, w1c);
  g2_gemm<<<3072, 256, 0, stream>>>(e_pad, w0p, b_ih0, xp, MM, NN, EPAD);
  g2_rnn<<<64, 256, 0, stream>>>(w_hh0, b_hh0, xp, h0, flags);
  g2_gemm<<<3072, 256, 0, stream>>>(h0, w1c, b_ih1, xp, MM, NN, 1024);
  g2_rnn<<<64, 256, 0, stream>>>(w_hh1, b_hh1, xp, h1, flags + 1024);
  g2_pool<<<64, 256, 0, stream>>>(h1, pooled);
  g2_head<<<64, 128, 0, stream>>>(pooled, w1, b1, w2, b2, (float*)d_out);
}

// Round 8
// 3763.841 us; speedup vs baseline: 2.5817x; 1.0220x over previous
//
#include <hip/hip_runtime.h>

// ---- problem constants ----
#define BB 64
#define TLEN 256
#define HH 512
#define GG 1536     // 3*H
#define EPAD 320    // E=300 padded to mult of 64
#define NN 3072     // 2*G (both directions stacked)
#define MM 16384    // T*B

typedef __attribute__((ext_vector_type(8))) __fp16 half8;
typedef __attribute__((ext_vector_type(4))) __fp16 half4;
typedef __attribute__((ext_vector_type(4))) float floatx4;

// ---- embedding gather + K-pad + fp32->fp16: e[t*64+b][0..320) ----
__global__ __launch_bounds__(256) void g2_embed(const int* __restrict__ x,
                                                const float* __restrict__ emb,
                                                __fp16* __restrict__ e) {
  int idx = blockIdx.x * 256 + threadIdx.x;   // chunk of 4 elems; total 16384*80
  int row = idx / 80;
  int c = idx - row * 80;
  int t = row >> 6, b = row & 63;
  half4 v = {0, 0, 0, 0};
  if (c < 75) {
    int xi = x[b * TLEN + t];
    float4 f = *(const float4*)&emb[(long)xi * 300 + c * 4];
    v[0] = (__fp16)f.x; v[1] = (__fp16)f.y; v[2] = (__fp16)f.z; v[3] = (__fp16)f.w;
  }
  *(half4*)&e[row * EPAD + c * 4] = v;
}

// ---- pad + convert w_ih0 [3072,300] fp32 -> [3072,320] fp16 ----
__global__ __launch_bounds__(256) void g2_padw(const float* __restrict__ w,
                                               __fp16* __restrict__ wp) {
  int idx = blockIdx.x * 256 + threadIdx.x;   // total 3072*80
  int row = idx / 80;
  int c = idx - row * 80;
  half4 v = {0, 0, 0, 0};
  if (c < 75) {
    float4 f = *(const float4*)&w[(long)row * 300 + c * 4];
    v[0] = (__fp16)f.x; v[1] = (__fp16)f.y; v[2] = (__fp16)f.z; v[3] = (__fp16)f.w;
  }
  *(half4*)&wp[row * EPAD + c * 4] = v;
}

// ---- fp32 -> fp16 bulk convert (chunks of 8) ----
__global__ __launch_bounds__(256) void g2_cvt(const float* __restrict__ src,
                                              __fp16* __restrict__ dst) {
  long idx = (long)blockIdx.x * 256 + threadIdx.x;
  float4 a = *(const float4*)&src[idx * 8];
  float4 b = *(const float4*)&src[idx * 8 + 4];
  half8 o;
  o[0] = (__fp16)a.x; o[1] = (__fp16)a.y; o[2] = (__fp16)a.z; o[3] = (__fp16)a.w;
  o[4] = (__fp16)b.x; o[5] = (__fp16)b.y; o[6] = (__fp16)b.z; o[7] = (__fp16)b.w;
  *(half8*)&dst[idx * 8] = o;
}

// ---- TN GEMM: C[M,N] fp16 = A[M,Kp] fp16 x W[N,Kp] fp16^T + bias[N](fp32) ----
__global__ __launch_bounds__(256) void g2_gemm(const __fp16* __restrict__ A,
                                               const __fp16* __restrict__ W,
                                               const float* __restrict__ bias,
                                               __fp16* __restrict__ C,
                                               int M, int N, int Kp) {
  __shared__ __fp16 As[128][72];
  __shared__ __fp16 Ws[128][72];
  const int nTiles = N >> 7;
  const int m0 = (blockIdx.x / nTiles) << 7;
  const int n0 = (blockIdx.x % nTiles) << 7;
  const int tid = threadIdx.x;
  const int lane = tid & 63, wv = tid >> 6;
  const int wm = (wv >> 1) << 6, wn = (wv & 1) << 6;
  const int nsub = lane & 15, quad = lane >> 4;

  floatx4 acc[4][4];
#pragma unroll
  for (int i = 0; i < 4; i++)
#pragma unroll
    for (int j = 0; j < 4; j++) acc[i][j] = (floatx4){0.f, 0.f, 0.f, 0.f};

  const int lr = tid >> 3;          // 0..31
  const int lc = (tid & 7) << 3;    // 0..56 step 8
  for (int ko = 0; ko < Kp; ko += 64) {
#pragma unroll
    for (int p = 0; p < 4; p++) {
      int r = lr + p * 32;
      *(half8*)&As[r][lc] = *(const half8*)&A[(long)(m0 + r) * Kp + ko + lc];
      *(half8*)&Ws[r][lc] = *(const half8*)&W[(long)(n0 + r) * Kp + ko + lc];
    }
    __syncthreads();
#pragma unroll
    for (int kk = 0; kk < 64; kk += 32) {
      half8 af[4], bf[4];
      const int kr = kk + (quad << 3);
#pragma unroll
      for (int i = 0; i < 4; i++) af[i] = *(const half8*)&As[wm + i * 16 + nsub][kr];
#pragma unroll
      for (int j = 0; j < 4; j++) bf[j] = *(const half8*)&Ws[wn + j * 16 + nsub][kr];
#pragma unroll
      for (int i = 0; i < 4; i++)
#pragma unroll
        for (int j = 0; j < 4; j++)
          acc[i][j] = __builtin_amdgcn_mfma_f32_16x16x32_f16(af[i], bf[j], acc[i][j], 0, 0, 0);
    }
    __syncthreads();
  }
#pragma unroll
  for (int j = 0; j < 4; j++) {
    int col = n0 + wn + j * 16 + nsub;
    float bv = bias[col];
#pragma unroll
    for (int i = 0; i < 4; i++) {
      int rb = m0 + wm + i * 16 + (quad << 2);
#pragma unroll
      for (int ii = 0; ii < 4; ii++)
        C[(long)(rb + ii) * N + col] = (__fp16)(acc[i][j][ii] + bv);
    }
  }
}

// ---- persistent bidirectional GRU recurrence ----
// grid 64 WGs x 256 thr. WG = (dir d, batch-group g of 32 rows, unit-tile uo of 32 units).
// Sync: per-producer int flag slots (one 64B line per group, double-buffered by
// step parity — a line only advances after all 16 WGs consumed its prior value,
// so plain stores are race-free). Producer: release fence + one RELAXED store
// (no RMW fan-in). Consumer: wave0 lane-parallel coalesced poll (1 LLC txn per
// round) + __all ballot, then acquire fence + pipelined plain h loads.
__global__ __launch_bounds__(256) void g2_rnn(const float* __restrict__ whh,  // [2][1536][512] fp32
                                              const float* __restrict__ bhh,  // [2][1536] fp32
                                              const __fp16* __restrict__ xp,  // [256][64][3072]
                                              __fp16* __restrict__ hout,      // [256][64][1024]
                                              int* __restrict__ flg) {        // [4 groups][2 parity][16 slots]
  __shared__ __fp16 Wl[96][520];    // [gate*32 + ulocal][512 (+8 pad)]
  __shared__ float hown[32][33];    // own h slice fp32 [brow][ulocal]
  const int bid = blockIdx.x;
  const int gi = bid & 3;           // d*2+g
  const int uo = bid >> 2;          // 0..15 (producer slot index)
  const int d = gi >> 1, g = gi & 1;
  const int tid = threadIdx.x;
  const int lane = tid & 63, wv = tid >> 6;
  const int U0 = uo << 5;           // 32 units per WG
  const int mb = wv & 1, ut = wv >> 1;
  const int nsub = lane & 15, quad = lane >> 4;
  const int bq = (g << 5) + (mb << 4);   // wave's global batch base (16 rows)
  const int ul = (ut << 4) + nsub;       // wave's unit (local 0..31)

  // ---- one-time: load + convert weights [3 gates][32 units][512] into LDS ----
  const float* wd = whh + (long)d * (GG * HH);
  for (int idx = tid; idx < 96 * 64; idx += 256) {
    int r = idx >> 6;               // 0..95
    int c = (idx & 63) << 3;        // 0..504 step 8
    int gate = r >> 5, u2 = r & 31;
    const float* src = &wd[(long)(gate * HH + U0 + u2) * HH + c];
    float4 a = *(const float4*)&src[0];
    float4 b = *(const float4*)&src[4];
    half8 o;
    o[0] = (__fp16)a.x; o[1] = (__fp16)a.y; o[2] = (__fp16)a.z; o[3] = (__fp16)a.w;
    o[4] = (__fp16)b.x; o[5] = (__fp16)b.y; o[6] = (__fp16)b.z; o[7] = (__fp16)b.w;
    *(half8*)&Wl[r][c] = o;
  }
  for (int i = tid; i < 32 * 33; i += 256) ((float*)hown)[i] = 0.f;
  __syncthreads();

  const float bhr = bhh[d * GG + U0 + ul];
  const float bhz = bhh[d * GG + HH + U0 + ul];
  const float bhn = bhh[d * GG + 2 * HH + U0 + ul];

  int* myflags = flg + gi * 32;     // [2 parity][16 slots]

  for (int s = 0; s < TLEN; s++) {
    const int tt = d ? (TLEN - 1 - s) : s;
    // prefetch xp for this step (independent of h -> overlaps the poll below)
    float xr[4], xz[4], xn[4];
    {
      const __fp16* xb0 = xp + (long)(tt * BB) * NN + d * GG + U0 + ul;
#pragma unroll
      for (int i = 0; i < 4; i++) {
        const __fp16* xb = xb0 + (long)(bq + (quad << 2) + i) * NN;
        xr[i] = (float)xb[0];
        xz[i] = (float)xb[HH];
        xn[i] = (float)xb[2 * HH];
      }
    }
    floatx4 ar = {0.f, 0.f, 0.f, 0.f}, az = ar, an = ar;
    if (s > 0) {
      const int pv = ((s - 1) & 127) + 1;          // value producers wrote for step s-1
      if (wv == 0) {
        // lane-parallel poll: lanes share 16 slots -> ONE coalesced load per round
        int* slot = &myflags[((s - 1) & 1) * 16 + (lane & 15)];
        while (!__all(__hip_atomic_load(slot, __ATOMIC_RELAXED, __HIP_MEMORY_SCOPE_AGENT) == pv)) {}
      }
      __syncthreads();
      __builtin_amdgcn_fence(__ATOMIC_ACQUIRE, "agent");  // one L1/L2 inv per step
      const int pt = d ? (tt + 1) : (tt - 1);
      const __fp16* hb = hout + ((long)(pt * BB + bq + nsub) * 1024) + d * HH + (quad << 3);
      // preload ALL h fragments — plain loads (post-fence => fresh), fully pipelined
      half8 hreg[16];
#pragma unroll
      for (int kk = 0; kk < 16; kk++)
        hreg[kk] = *(const half8*)&hb[kk * 32];
#pragma unroll
      for (int kk = 0; kk < 16; kk++) {
        const int kcol = (kk << 5) + (quad << 3);
        half8 br = *(const half8*)&Wl[(ut << 4) + nsub][kcol];
        half8 bz = *(const half8*)&Wl[32 + (ut << 4) + nsub][kcol];
        half8 bn = *(const half8*)&Wl[64 + (ut << 4) + nsub][kcol];
        ar = __builtin_amdgcn_mfma_f32_16x16x32_f16(hreg[kk], br, ar, 0, 0, 0);
        az = __builtin_amdgcn_mfma_f32_16x16x32_f16(hreg[kk], bz, az, 0, 0, 0);
        an = __builtin_amdgcn_mfma_f32_16x16x32_f16(hreg[kk], bn, an, 0, 0, 0);
      }
    }
    // epilogue -> hown (fp32, exact self-recurrence path)
#pragma unroll
    for (int i = 0; i < 4; i++) {
      int brow = (mb << 4) + (quad << 2) + i;   // 0..31 within group
      float grv = ar[i] + xr[i] + bhr;
      float gzv = az[i] + xz[i] + bhz;
      float gnv = an[i] + bhn;                  // recurrent part of n-gate (+b_hh)
      float rg = 1.f / (1.f + __expf(-grv));
      float zg = 1.f / (1.f + __expf(-gzv));
      float ex = __expf(2.f * (xn[i] + rg * gnv));
      float ng = 1.f - 2.f / (ex + 1.f);        // tanh
      float hold = hown[brow][ul];
      hown[brow][ul] = (1.f - zg) * ng + zg * hold;
    }
    __syncthreads();
    // coalesced publish: 32 rows x 32 units as half8 volatile (write-through) stores
    if (tid < 128) {
      int br = tid >> 2;            // 0..31
      int c = (tid & 3) << 3;       // 0..24 step 8
      half8 o;
#pragma unroll
      for (int q = 0; q < 8; q++) o[q] = (__fp16)hown[br][c + q];
      *(volatile half8*)&hout[(long)(tt * BB + (g << 5) + br) * 1024 + d * HH + U0 + c] = o;
    }
    __syncthreads();   // vmcnt(0) drain before barrier -> stores done
    if (tid == 0) {
      __builtin_amdgcn_fence(__ATOMIC_RELEASE, "agent");  // L2 wb: h at coherence point
      __hip_atomic_store(&myflags[(s & 1) * 16 + uo], (s & 127) + 1,
                         __ATOMIC_RELAXED, __HIP_MEMORY_SCOPE_AGENT);  // fire-and-forget
    }
  }
}

// ---- max-pool over T ----
__global__ __launch_bounds__(256) void g2_pool(const __fp16* __restrict__ h1,
                                               float* __restrict__ pooled) {
  int b = blockIdx.x;
  int j0 = threadIdx.x * 4;
  float m[4] = {-3e38f, -3e38f, -3e38f, -3e38f};
  const __fp16* p = h1 + b * 1024 + j0;
  for (int t = 0; t < TLEN; t++) {
    half4 v = *(const half4*)(p + (long)t * BB * 1024);
#pragma unroll
    for (int q = 0; q < 4; q++) m[q] = fmaxf(m[q], (float)v[q]);
  }
  float* o = pooled + b * 1024 + j0;
#pragma unroll
  for (int q = 0; q < 4; q++) o[q] = m[q];
}

// ---- classifier head (all fp32) ----
__global__ __launch_bounds__(128) void g2_head(const float* __restrict__ pooled,
                                               const float* __restrict__ w1,
                                               const float* __restrict__ b1,
                                               const float* __restrict__ w2,
                                               const float* __restrict__ b2,
                                               float* __restrict__ out) {
  __shared__ float pl[1024];
  __shared__ float hid[128];
  int b = blockIdx.x, j = threadIdx.x;
  for (int k = j; k < 1024; k += 128) pl[k] = pooled[b * 1024 + k];
  __syncthreads();
  float acc = b1[j];
  const float* wr = w1 + (long)j * 1024;
  for (int k = 0; k < 1024; k += 4) {
    float4 w = *(const float4*)&wr[k];
    acc += pl[k] * w.x + pl[k + 1] * w.y + pl[k + 2] * w.z + pl[k + 3] * w.w;
  }
  hid[j] = fmaxf(acc, 0.f);
  __syncthreads();
  if (j < 2) {
    float a = b2[j];
    for (int k = 0; k < 128; k++) a += hid[k] * w2[j * 128 + k];
    out[b * 2 + j] = a;
  }
}

extern "C" void kernel_launch(void* const* d_in, const int* in_sizes, int n_in,
                              void* d_out, int out_size, void* d_ws, size_t ws_size,
                              hipStream_t stream) {
  (void)in_sizes; (void)n_in; (void)out_size; (void)ws_size;
  const int* x = (const int*)d_in[0];
  const float* emb = (const float*)d_in[1];
  const float* w_ih0 = (const float*)d_in[2];
  const float* w_hh0 = (const float*)d_in[3];
  const float* b_ih0 = (const float*)d_in[4];
  const float* b_hh0 = (const float*)d_in[5];
  const float* w_ih1 = (const float*)d_in[6];
  const float* w_hh1 = (const float*)d_in[7];
  const float* b_ih1 = (const float*)d_in[8];
  const float* b_hh1 = (const float*)d_in[9];
  const float* w1 = (const float*)d_in[10];
  const float* b1 = (const float*)d_in[11];
  const float* w2 = (const float*)d_in[12];
  const float* b2 = (const float*)d_in[13];

  // ---- workspace layout (total 186,785,792 B ~= 178 MiB) ----
  char* ws = (char*)d_ws;
  __fp16* xp = (__fp16*)(ws + 0);                  // 16384*3072*2 = 100,663,296
  __fp16* h0 = (__fp16*)(ws + 100663296);          // 16384*1024*2 =  33,554,432
  __fp16* h1 = (__fp16*)(ws + 134217728);          //                 33,554,432
  __fp16* e_pad = (__fp16*)(ws + 167772160);       // 16384*320*2  =  10,485,760
  __fp16* w0p = (__fp16*)(ws + 178257920);         // 3072*320*2   =   1,966,080
  __fp16* w1c = (__fp16*)(ws + 180224000);         // 3072*1024*2  =   6,291,456
  float* pooled = (float*)(ws + 186515456);        // 64*1024*4    =     262,144
  int* flags = (int*)(ws + 186777600);             //                      8,192

  (void)hipMemsetAsync(flags, 0, 8192, stream);
  g2_embed<<<5120, 256, 0, stream>>>(x, emb, e_pad);
  g2_padw<<<960, 256, 0, stream>>>(w_ih0, w0p);
  g2_cvt<<<1536, 256, 0, stream>>>(w_ih1, w1c);
  g2_gemm<<<3072, 256, 0, stream>>>(e_pad, w0p, b_ih0, xp, MM, NN, EPAD);
  g2_rnn<<<64, 256, 0, stream>>>(w_hh0, b_hh0, xp, h0, flags);
  g2_gemm<<<3072, 256, 0, stream>>>(h0, w1c, b_ih1, xp, MM, NN, 1024);
  g2_rnn<<<64, 256, 0, stream>>>(w_hh1, b_hh1, xp, h1, flags + 128);
  g2_pool<<<64, 256, 0, stream>>>(h1, pooled);
  g2_head<<<64, 128, 0, stream>>>(pooled, w1, b1, w2, b2, (float*)d_out);
}